// Round 4
// baseline (551.404 us; speedup 1.0000x reference)
//
#include <hip/hip_runtime.h>
#include <hip/hip_bf16.h>

#define Bq 4
#define Tq 2048
#define Dq 1024
#define Hq 16
#define HSq 64
#define EPSq 1e-5f

typedef __attribute__((ext_vector_type(8))) short s16x8;
typedef __attribute__((ext_vector_type(4))) float f32x4;

#define GLL16(g, l)                                                        \
    __builtin_amdgcn_global_load_lds(                                      \
        (const __attribute__((address_space(1))) void*)(g),                \
        (__attribute__((address_space(3))) void*)(l), 16, 0, 0)

#define PH_BAR() do { __builtin_amdgcn_sched_barrier(0);                   \
                      __builtin_amdgcn_s_barrier();                        \
                      __builtin_amdgcn_sched_barrier(0); } while (0)

__device__ __forceinline__ ushort f2bf(float f) {
    union { float f; unsigned u; } x; x.f = f;
    unsigned r = x.u + 0x7fffu + ((x.u >> 16) & 1u);
    return (ushort)(r >> 16);
}

// ---------------- LayerNorm: fp32 out + bf16 out ----------------
__global__ __launch_bounds__(256) void ln_bf16(const float* __restrict__ x,
                                               const float* __restrict__ g,
                                               const float* __restrict__ bb,
                                               float* __restrict__ y,
                                               ushort* __restrict__ y16) {
    __shared__ float sdata[8];
    int row = blockIdx.x;
    const float4* xr = (const float4*)(x + (size_t)row * Dq);
    float4 v = xr[threadIdx.x];
    float s  = v.x + v.y + v.z + v.w;
    float ss = v.x*v.x + v.y*v.y + v.z*v.z + v.w*v.w;
    for (int off = 32; off; off >>= 1) {
        s  += __shfl_down(s,  off);
        ss += __shfl_down(ss, off);
    }
    int lane = threadIdx.x & 63, wid = threadIdx.x >> 6;
    if (lane == 0) { sdata[wid] = s; sdata[4 + wid] = ss; }
    __syncthreads();
    if (threadIdx.x == 0) {
        sdata[0] = sdata[0] + sdata[1] + sdata[2] + sdata[3];
        sdata[4] = sdata[4] + sdata[5] + sdata[6] + sdata[7];
    }
    __syncthreads();
    float mu  = sdata[0] * (1.f / Dq);
    float var = sdata[4] * (1.f / Dq) - mu * mu;
    float inv = rsqrtf(var + EPSq);
    float4 gv = ((const float4*)g)[threadIdx.x];
    float4 bv = ((const float4*)bb)[threadIdx.x];
    float4 o;
    o.x = (v.x - mu) * inv * gv.x + bv.x;
    o.y = (v.y - mu) * inv * gv.y + bv.y;
    o.z = (v.z - mu) * inv * gv.z + bv.z;
    o.w = (v.w - mu) * inv * gv.w + bv.w;
    ((float4*)(y + (size_t)row * Dq))[threadIdx.x] = o;
    ushort4 u4;
    u4.x = f2bf(o.x); u4.y = f2bf(o.y); u4.z = f2bf(o.z); u4.w = f2bf(o.w);
    *(ushort4*)(y16 + (size_t)row * Dq + threadIdx.x * 4) = u4;
}

// ---------------- repack Wq/Wk/Wv [H,D,HS] -> bf16 [3D][D] transposed; Wq scaled by 1/32 ----------------
__global__ __launch_bounds__(256) void repack_qkvT(const float* __restrict__ Wqm,
                                                   const float* __restrict__ Wkm,
                                                   const float* __restrict__ Wvm,
                                                   ushort* __restrict__ out) {
    __shared__ float tile[64][65];
    int bid = blockIdx.x;          // p(3) x hh(16) x kt(16)
    int p  = bid >> 8;
    int hh = (bid >> 4) & 15;
    int kt = bid & 15;
    int k0 = kt * 64;
    const float* W = (p == 0) ? Wqm : ((p == 1) ? Wkm : Wvm);
    float scale = (p == 0) ? 0.03125f : 1.0f;
    int j  = threadIdx.x & 63;
    int i0 = threadIdx.x >> 6;
#pragma unroll
    for (int r = 0; r < 16; r++) {
        int i = r * 4 + i0;
        tile[i][j] = W[(size_t)hh * (Dq * HSq) + (size_t)(k0 + i) * HSq + j];
    }
    __syncthreads();
#pragma unroll
    for (int r = 0; r < 16; r++) {
        int i = r * 4 + i0;
        out[(size_t)(p * Dq + hh * HSq + i) * Dq + k0 + j] = f2bf(tile[j][i] * scale);
    }
}

// ---------------- transpose+cvt: in fp32 [K][N] -> out bf16 [N][K] ----------------
__global__ __launch_bounds__(256) void transpose_cvt(const float* __restrict__ in,
                                                     ushort* __restrict__ out,
                                                     int K, int N) {
    __shared__ float tile[64][65];
    int k0 = blockIdx.y * 64, n0 = blockIdx.x * 64;
    int j  = threadIdx.x & 63;
    int i0 = threadIdx.x >> 6;
#pragma unroll
    for (int r = 0; r < 16; r++) {
        int i = r * 4 + i0;
        tile[i][j] = in[(size_t)(k0 + i) * N + n0 + j];
    }
    __syncthreads();
#pragma unroll
    for (int r = 0; r < 16; r++) {
        int i = r * 4 + i0;
        out[(size_t)(n0 + i) * K + k0 + j] = f2bf(tile[j][i]);
    }
}

// ---------------- bf16 MFMA GEMM, m201-style 8-phase 256x256 pipeline ----------------
// BM=BN=256, BK=64, 512 thr (2x4 waves, 128x64 out/wave, acc[8][4]).
// LDS 128 KiB: A/B each 2 dbuf x 2 half x [128][64] bf16. One iter = 2 K-tiles
// (even->dbuf0, odd->dbuf1), 8 phases x 16 MFMA. One half-tile staged per phase
// (2 x GLL16); gates ONLY at ph4/ph8, both vmcnt(4) (each drains exactly one
// complete K-tile; 6 half-tiles max in flight). Ledger: A halves of tile t
// last read ph3(e)/ph7(o); B halves ph2/ph6; stages placed strictly after.
// XOR-swizzle (chunk ^= row&7) via pre-swizzled global source + same XOR on
// ds_read_b128 (round-3-verified: 0 bank conflicts).
__global__ __launch_bounds__(512, 2) void gemm_8ph(const ushort* __restrict__ A,
                                                   const ushort* __restrict__ BT,
                                                   const float* __restrict__ bias,
                                                   const float* __restrict__ resid,
                                                   void* __restrict__ Cp,
                                                   ushort* __restrict__ vtg,
                                                   int M, int N, int K,
                                                   int lda, int ldc,
                                                   int relu, int out_bf16) {
    __shared__ ushort lds[65536];                  // 128 KiB
    ushort* Al = lds;                              // [(d*2+h)][128][64]
    ushort* Bl = lds + 32768;

    int tid = threadIdx.x;
    int w = tid >> 6, lane = tid & 63;
    int lm = lane & 15, quad = lane >> 4;
    int wm = w >> 2, wn = w & 3;                   // 2 x 4 wave grid

    int nwg = gridDim.x, bid = blockIdx.x, wk = bid;
    if ((nwg & 7) == 0) { int cpx = nwg >> 3; wk = (bid & 7) * cpx + (bid >> 3); }
    int mtiles = M >> 8;
    int rt = wk % mtiles, ct = wk / mtiles;
    int row0 = rt << 8, col0 = ct << 8;

    // staging source (pre-swizzled): lane writes phys chunk (lane&7) of local
    // row w*8+(lane>>3) (+64); phys chunk c of row r holds logical c^(r&7)
    int cswz = (lane & 7) ^ (lane >> 3);
    int srow = w * 8 + (lane >> 3);
    const ushort* pA = A  + (size_t)(row0 + srow) * lda + cswz * 8;
    const ushort* pB = BT + (size_t)(col0 + srow) * K  + cswz * 8;

    auto stA = [&](int h, int t) {                 // half h of K-tile t -> dbuf t&1
        const ushort* g = pA + (size_t)(h * 128) * lda + (size_t)t * 64;
        ushort* l = Al + ((t & 1) * 2 + h) * 8192 + w * 512;
        GLL16(g, l);
        GLL16(g + (size_t)64 * lda, l + 4096);
    };
    auto stB = [&](int h, int t) {
        const ushort* g = pB + (size_t)(h * 128) * K + (size_t)t * 64;
        ushort* l = Bl + ((t & 1) * 2 + h) * 8192 + w * 512;
        GLL16(g, l);
        GLL16(g + (size_t)64 * K, l + 4096);
    };

    int swq0 = (quad * 8) ^ ((lm & 7) << 3);
    int swq1 = (32 + quad * 8) ^ ((lm & 7) << 3);

    // per-wave ds_read bases (A half = wm; B half = wn>>1, row offset (wn&1)*64)
    const ushort* A0b = Al + wm * 8192 + lm * 64;              // dbuf0
    const ushort* A1b = Al + (2 + wm) * 8192 + lm * 64;        // dbuf1
    const ushort* B0b = Bl + (wn >> 1) * 8192 + ((wn & 1) * 64 + lm) * 64;
    const ushort* B1b = Bl + (2 + (wn >> 1)) * 8192 + ((wn & 1) * 64 + lm) * 64;

    f32x4 zero = {0.f, 0.f, 0.f, 0.f};
    f32x4 acc[8][4];
#pragma unroll
    for (int i = 0; i < 8; i++)
#pragma unroll
        for (int jj = 0; jj < 4; jj++) acc[i][jj] = zero;

    int nkt = K >> 6;                              // even, >= 16 here
    int T = nkt >> 1;

    // prologue: tile0 complete + tile1 B halves; gate drains tile0 exactly
    stB(0, 0); __builtin_amdgcn_sched_barrier(0);
    stB(1, 0); __builtin_amdgcn_sched_barrier(0);
    stA(0, 0); __builtin_amdgcn_sched_barrier(0);
    stA(1, 0); __builtin_amdgcn_sched_barrier(0);
    stB(0, 1); __builtin_amdgcn_sched_barrier(0);
    stB(1, 1);
    __builtin_amdgcn_sched_barrier(0);
    asm volatile("s_waitcnt vmcnt(4)" ::: "memory");
    __builtin_amdgcn_s_barrier();
    __builtin_amdgcn_sched_barrier(0);

    for (int j = 0; j < T; ++j) {
        int o = 2 * j + 1, e2 = 2 * j + 2, o2 = 2 * j + 3;
        const bool stg = (j + 1 < T);
        s16x8 a[4][2], b[2][2], c[2][2];

        // ---- ph1: read A[e] lo + B[e] lo; stage A0(o)->dbuf1 ----
#pragma unroll
        for (int m = 0; m < 4; m++) {
            a[m][0] = *(const s16x8*)(A0b + m * 1024 + swq0);
            a[m][1] = *(const s16x8*)(A0b + m * 1024 + swq1);
        }
#pragma unroll
        for (int n = 0; n < 2; n++) {
            b[n][0] = *(const s16x8*)(B0b + n * 1024 + swq0);
            b[n][1] = *(const s16x8*)(B0b + n * 1024 + swq1);
        }
        stA(0, o);
        PH_BAR();
        __builtin_amdgcn_s_setprio(1);
#pragma unroll
        for (int m = 0; m < 4; m++)
#pragma unroll
            for (int n = 0; n < 2; n++) {
                f32x4 t = __builtin_amdgcn_mfma_f32_16x16x32_bf16(a[m][0], b[n][0], acc[m][n], 0, 0, 0);
                acc[m][n] = __builtin_amdgcn_mfma_f32_16x16x32_bf16(a[m][1], b[n][1], t, 0, 0, 0);
            }
        __builtin_amdgcn_s_setprio(0);
        PH_BAR();

        // ---- ph2: read B[e] hi; stage A1(o) ----
#pragma unroll
        for (int n = 0; n < 2; n++) {
            c[n][0] = *(const s16x8*)(B0b + (n + 2) * 1024 + swq0);
            c[n][1] = *(const s16x8*)(B0b + (n + 2) * 1024 + swq1);
        }
        stA(1, o);
        PH_BAR();
        __builtin_amdgcn_s_setprio(1);
#pragma unroll
        for (int m = 0; m < 4; m++)
#pragma unroll
            for (int n = 0; n < 2; n++) {
                f32x4 t = __builtin_amdgcn_mfma_f32_16x16x32_bf16(a[m][0], c[n][0], acc[m][n + 2], 0, 0, 0);
                acc[m][n + 2] = __builtin_amdgcn_mfma_f32_16x16x32_bf16(a[m][1], c[n][1], t, 0, 0, 0);
            }
        __builtin_amdgcn_s_setprio(0);
        PH_BAR();

        // ---- ph3: read A[e] hi; stage B0(e2)->dbuf0 (B[e] reads done ph2) ----
#pragma unroll
        for (int m = 0; m < 4; m++) {
            a[m][0] = *(const s16x8*)(A0b + (m + 4) * 1024 + swq0);
            a[m][1] = *(const s16x8*)(A0b + (m + 4) * 1024 + swq1);
        }
        if (stg) stB(0, e2);
        PH_BAR();
        __builtin_amdgcn_s_setprio(1);
#pragma unroll
        for (int m = 0; m < 4; m++)
#pragma unroll
            for (int n = 0; n < 2; n++) {
                f32x4 t = __builtin_amdgcn_mfma_f32_16x16x32_bf16(a[m][0], b[n][0], acc[m + 4][n], 0, 0, 0);
                acc[m + 4][n] = __builtin_amdgcn_mfma_f32_16x16x32_bf16(a[m][1], b[n][1], t, 0, 0, 0);
            }
        __builtin_amdgcn_s_setprio(0);
        PH_BAR();

        // ---- ph4: stage B1(e2); MFMA; GATE(tile o complete) ----
        if (stg) stB(1, e2);
        PH_BAR();
        __builtin_amdgcn_s_setprio(1);
#pragma unroll
        for (int m = 0; m < 4; m++)
#pragma unroll
            for (int n = 0; n < 2; n++) {
                f32x4 t = __builtin_amdgcn_mfma_f32_16x16x32_bf16(a[m][0], c[n][0], acc[m + 4][n + 2], 0, 0, 0);
                acc[m + 4][n + 2] = __builtin_amdgcn_mfma_f32_16x16x32_bf16(a[m][1], c[n][1], t, 0, 0, 0);
            }
        __builtin_amdgcn_s_setprio(0);
        __builtin_amdgcn_sched_barrier(0);
        if (stg) { asm volatile("s_waitcnt vmcnt(4)" ::: "memory"); }
        else     { asm volatile("s_waitcnt vmcnt(0)" ::: "memory"); }
        __builtin_amdgcn_s_barrier();
        __builtin_amdgcn_sched_barrier(0);

        // ---- ph5: read A[o] lo + B[o] lo; stage A0(e2) (A[e] reads done ph3) ----
#pragma unroll
        for (int m = 0; m < 4; m++) {
            a[m][0] = *(const s16x8*)(A1b + m * 1024 + swq0);
            a[m][1] = *(const s16x8*)(A1b + m * 1024 + swq1);
        }
#pragma unroll
        for (int n = 0; n < 2; n++) {
            b[n][0] = *(const s16x8*)(B1b + n * 1024 + swq0);
            b[n][1] = *(const s16x8*)(B1b + n * 1024 + swq1);
        }
        if (stg) stA(0, e2);
        PH_BAR();
        __builtin_amdgcn_s_setprio(1);
#pragma unroll
        for (int m = 0; m < 4; m++)
#pragma unroll
            for (int n = 0; n < 2; n++) {
                f32x4 t = __builtin_amdgcn_mfma_f32_16x16x32_bf16(a[m][0], b[n][0], acc[m][n], 0, 0, 0);
                acc[m][n] = __builtin_amdgcn_mfma_f32_16x16x32_bf16(a[m][1], b[n][1], t, 0, 0, 0);
            }
        __builtin_amdgcn_s_setprio(0);
        PH_BAR();

        // ---- ph6: read B[o] hi; stage A1(e2) ----
#pragma unroll
        for (int n = 0; n < 2; n++) {
            c[n][0] = *(const s16x8*)(B1b + (n + 2) * 1024 + swq0);
            c[n][1] = *(const s16x8*)(B1b + (n + 2) * 1024 + swq1);
        }
        if (stg) stA(1, e2);
        PH_BAR();
        __builtin_amdgcn_s_setprio(1);
#pragma unroll
        for (int m = 0; m < 4; m++)
#pragma unroll
            for (int n = 0; n < 2; n++) {
                f32x4 t = __builtin_amdgcn_mfma_f32_16x16x32_bf16(a[m][0], c[n][0], acc[m][n + 2], 0, 0, 0);
                acc[m][n + 2] = __builtin_amdgcn_mfma_f32_16x16x32_bf16(a[m][1], c[n][1], t, 0, 0, 0);
            }
        __builtin_amdgcn_s_setprio(0);
        PH_BAR();

        // ---- ph7: read A[o] hi; stage B0(o2)->dbuf1 (B[o] reads done ph6) ----
#pragma unroll
        for (int m = 0; m < 4; m++) {
            a[m][0] = *(const s16x8*)(A1b + (m + 4) * 1024 + swq0);
            a[m][1] = *(const s16x8*)(A1b + (m + 4) * 1024 + swq1);
        }
        if (stg) stB(0, o2);
        PH_BAR();
        __builtin_amdgcn_s_setprio(1);
#pragma unroll
        for (int m = 0; m < 4; m++)
#pragma unroll
            for (int n = 0; n < 2; n++) {
                f32x4 t = __builtin_amdgcn_mfma_f32_16x16x32_bf16(a[m][0], b[n][0], acc[m + 4][n], 0, 0, 0);
                acc[m + 4][n] = __builtin_amdgcn_mfma_f32_16x16x32_bf16(a[m][1], b[n][1], t, 0, 0, 0);
            }
        __builtin_amdgcn_s_setprio(0);
        PH_BAR();

        // ---- ph8: stage B1(o2); MFMA; GATE(tile e2 complete) ----
        if (stg) stB(1, o2);
        PH_BAR();
        __builtin_amdgcn_s_setprio(1);
#pragma unroll
        for (int m = 0; m < 4; m++)
#pragma unroll
            for (int n = 0; n < 2; n++) {
                f32x4 t = __builtin_amdgcn_mfma_f32_16x16x32_bf16(a[m][0], c[n][0], acc[m + 4][n + 2], 0, 0, 0);
                acc[m + 4][n + 2] = __builtin_amdgcn_mfma_f32_16x16x32_bf16(a[m][1], c[n][1], t, 0, 0, 0);
            }
        __builtin_amdgcn_s_setprio(0);
        if (stg) {
            __builtin_amdgcn_sched_barrier(0);
            asm volatile("s_waitcnt vmcnt(4)" ::: "memory");
            __builtin_amdgcn_s_barrier();
            __builtin_amdgcn_sched_barrier(0);
        }
    }

    if (vtg && col0 >= 2048) {
        // V part: write transposed [B*H*HS][T], 4 consecutive t per ushort4
#pragma unroll
        for (int m = 0; m < 8; m++) {
            int r0 = row0 + wm * 128 + m * 16 + quad * 4;   // t base (mult of 4)
            int bb = r0 >> 11;
            int t  = r0 & (Tq - 1);
#pragma unroll
            for (int nf = 0; nf < 4; nf++) {
                int hsg = col0 - 2048 + wn * 64 + nf * 16 + lm;   // 0..1023
                ushort4 u;
                u.x = f2bf(acc[m][nf][0]);
                u.y = f2bf(acc[m][nf][1]);
                u.z = f2bf(acc[m][nf][2]);
                u.w = f2bf(acc[m][nf][3]);
                *(ushort4*)(vtg + ((size_t)(bb * Hq + (hsg >> 6)) * HSq + (hsg & 63)) * Tq + t) = u;
            }
        }
        return;
    }

    float bcol[4];
#pragma unroll
    for (int nf = 0; nf < 4; nf++)
        bcol[nf] = bias ? bias[col0 + wn * 64 + nf * 16 + lm] : 0.f;

#pragma unroll
    for (int m = 0; m < 8; m++) {
#pragma unroll
        for (int p = 0; p < 4; p++) {
            int r = row0 + wm * 128 + m * 16 + quad * 4 + p;
#pragma unroll
            for (int nf = 0; nf < 4; nf++) {
                int cc = col0 + wn * 64 + nf * 16 + lm;
                float v = acc[m][nf][p] + bcol[nf];
                if (relu) v = fmaxf(v, 0.f);
                if (resid) v += resid[(size_t)r * ldc + cc];
                if (out_bf16) ((ushort*)Cp)[(size_t)r * ldc + cc] = f2bf(v);
                else          ((float*)Cp)[(size_t)r * ldc + cc] = v;
            }
        }
    }
}

// ---------------- bf16 MFMA GEMM, counted-vmcnt 2-phase (proj; round-3 proven) ----------------
__global__ __launch_bounds__(512, 2) void gemm_mp(const ushort* __restrict__ A,
                                                  const ushort* __restrict__ BT,
                                                  const float* __restrict__ bias,
                                                  const float* __restrict__ resid,
                                                  void* __restrict__ Cp,
                                                  ushort* __restrict__ vtg,
                                                  int M, int N, int K,
                                                  int lda, int ldc,
                                                  int relu, int out_bf16) {
    __shared__ ushort lds[2 * 8192 + 3 * 16384];   // 128 KiB
    ushort* Alds = lds;
    ushort* Blds = lds + 2 * 8192;

    int tid = threadIdx.x;
    int w = tid >> 6, lane = tid & 63;
    int lm = lane & 15, quad = lane >> 4;
    int wm = w >> 2, wn = w & 3;

    int nwg = gridDim.x;
    int bid = blockIdx.x;
    int wk = bid;
    if ((nwg & 7) == 0) { int cpx = nwg >> 3; wk = (bid & 7) * cpx + (bid >> 3); }
    int mtiles = M >> 7;
    int rt = wk % mtiles, ct = wk / mtiles;
    int row0 = rt << 7, col0 = ct << 8;

    int cswz = (lane & 7) ^ (lane >> 3);
    int srow = w * 8 + (lane >> 3);
    const ushort* pA = A  + (size_t)(row0 + srow) * lda + cswz * 8;
    const ushort* pB = BT + (size_t)(col0 + srow) * K  + cswz * 8;

    auto stageA = [&](int slot, int t) {
        const ushort* g = pA + (size_t)t * 64;
        ushort* l = Alds + slot * 8192 + w * 512;
        GLL16(g, l);
        GLL16(g + (size_t)64 * lda, l + 4096);
    };
    auto stageB = [&](int slot, int t, int h) {
        const ushort* g = pB + (size_t)t * 64 + (size_t)(h * 128) * K;
        ushort* l = Blds + slot * 16384 + h * 8192 + w * 512;
        GLL16(g, l);
        GLL16(g + (size_t)64 * K, l + 4096);
    };

    int swq0 = (quad * 8) ^ ((lm & 7) << 3);
    int swq1 = (32 + quad * 8) ^ ((lm & 7) << 3);

    f32x4 zero = {0.f, 0.f, 0.f, 0.f};
    f32x4 acc[4][4];
#pragma unroll
    for (int i = 0; i < 4; i++)
#pragma unroll
        for (int jj = 0; jj < 4; jj++) acc[i][jj] = zero;

    int nkt = K >> 6;

    stageA(0, 0);
    stageB(0, 0, 0); stageB(0, 0, 1);
    stageB(1, 1, 0); stageB(1, 1, 1);
    __builtin_amdgcn_sched_barrier(0);
    asm volatile("s_waitcnt vmcnt(4)" ::: "memory");
    __builtin_amdgcn_s_barrier();
    __builtin_amdgcn_sched_barrier(0);

    int sA = 0, sB = 0;
    for (int t = 0; t < nkt; ++t) {
        const bool stA = (t + 1 < nkt);
        const bool stB = (t + 2 < nkt);
        int sB2 = sB + 2; if (sB2 >= 3) sB2 -= 3;
        const ushort* Ab = Alds + sA * 8192  + (wm * 64 + lm) * 64;
        const ushort* Bb = Blds + sB * 16384 + (wn * 64 + lm) * 64;
        s16x8 a[4][2], b0[2][2], b1[2][2];

#pragma unroll
        for (int m = 0; m < 4; m++) {
            a[m][0] = *(const s16x8*)(Ab + m * 1024 + swq0);
            a[m][1] = *(const s16x8*)(Ab + m * 1024 + swq1);
        }
#pragma unroll
        for (int nf = 0; nf < 2; nf++) {
            b0[nf][0] = *(const s16x8*)(Bb + nf * 1024 + swq0);
            b0[nf][1] = *(const s16x8*)(Bb + nf * 1024 + swq1);
        }
        if (stA) stageA(sA ^ 1, t + 1);
        if (stB) stageB(sB2, t + 2, 0);
        PH_BAR();
        __builtin_amdgcn_s_setprio(1);
#pragma unroll
        for (int m = 0; m < 4; m++)
#pragma unroll
            for (int nf = 0; nf < 2; nf++) {
                f32x4 tt = __builtin_amdgcn_mfma_f32_16x16x32_bf16(a[m][0], b0[nf][0], acc[m][nf], 0, 0, 0);
                acc[m][nf] = __builtin_amdgcn_mfma_f32_16x16x32_bf16(a[m][1], b0[nf][1], tt, 0, 0, 0);
            }
        __builtin_amdgcn_s_setprio(0);
        PH_BAR();

#pragma unroll
        for (int nf = 0; nf < 2; nf++) {
            b1[nf][0] = *(const s16x8*)(Bb + (nf + 2) * 1024 + swq0);
            b1[nf][1] = *(const s16x8*)(Bb + (nf + 2) * 1024 + swq1);
        }
        if (stB) stageB(sB2, t + 2, 1);
        PH_BAR();
        __builtin_amdgcn_s_setprio(1);
#pragma unroll
        for (int m = 0; m < 4; m++)
#pragma unroll
            for (int nf = 0; nf < 2; nf++) {
                f32x4 tt = __builtin_amdgcn_mfma_f32_16x16x32_bf16(a[m][0], b1[nf][0], acc[m][nf + 2], 0, 0, 0);
                acc[m][nf + 2] = __builtin_amdgcn_mfma_f32_16x16x32_bf16(a[m][1], b1[nf][1], tt, 0, 0, 0);
            }
        __builtin_amdgcn_s_setprio(0);
        __builtin_amdgcn_sched_barrier(0);
        if (stB)      { asm volatile("s_waitcnt vmcnt(4)" ::: "memory"); }
        else if (stA) { asm volatile("s_waitcnt vmcnt(0)" ::: "memory"); }
        __builtin_amdgcn_s_barrier();
        __builtin_amdgcn_sched_barrier(0);

        sA ^= 1;
        sB += 1; if (sB >= 3) sB -= 3;
    }

    if (vtg && col0 >= 2048) {
#pragma unroll
        for (int m = 0; m < 4; m++) {
            int r0 = row0 + wm * 64 + m * 16 + quad * 4;
            int bb = r0 >> 11;
            int t  = r0 & (Tq - 1);
#pragma unroll
            for (int nf = 0; nf < 4; nf++) {
                int hsg = col0 - 2048 + wn * 64 + nf * 16 + lm;
                ushort4 u;
                u.x = f2bf(acc[m][nf][0]);
                u.y = f2bf(acc[m][nf][1]);
                u.z = f2bf(acc[m][nf][2]);
                u.w = f2bf(acc[m][nf][3]);
                *(ushort4*)(vtg + ((size_t)(bb * Hq + (hsg >> 6)) * HSq + (hsg & 63)) * Tq + t) = u;
            }
        }
        return;
    }

    float bcol[4];
#pragma unroll
    for (int nf = 0; nf < 4; nf++)
        bcol[nf] = bias ? bias[col0 + wn * 64 + nf * 16 + lm] : 0.f;

#pragma unroll
    for (int m = 0; m < 4; m++) {
#pragma unroll
        for (int p = 0; p < 4; p++) {
            int r = row0 + wm * 64 + m * 16 + quad * 4 + p;
#pragma unroll
            for (int nf = 0; nf < 4; nf++) {
                int cc = col0 + wn * 64 + nf * 16 + lm;
                float v = acc[m][nf][p] + bcol[nf];
                if (relu) v = fmaxf(v, 0.f);
                if (resid) v += resid[(size_t)r * ldc + cc];
                if (out_bf16) ((ushort*)Cp)[(size_t)r * ldc + cc] = f2bf(v);
                else          ((float*)Cp)[(size_t)r * ldc + cc] = v;
            }
        }
    }
}

// ---------------- MFMA flash attention, complement-paired q-tiles ----------------
__global__ __launch_bounds__(256) void attn_mfma(const ushort* __restrict__ qkv,
                                                 const ushort* __restrict__ VtG,
                                                 ushort* __restrict__ o16) {
    __shared__ ushort Ks[64 * 72];
    __shared__ ushort Vt[64 * 64];
    __shared__ ushort Ps[4 * 16 * 72];

    int gid = blockIdx.x;
    int b  = gid >> 8;
    int hh = (gid >> 4) & 15;
    int pr = (gid + 7 * b) & 15;
    int qa = pr;
    int qb = 31 - pr;

    int tid = threadIdx.x;
    int w = tid >> 6, lane = tid & 63;
    int lm = lane & 15, quad = lane >> 4;

    const int rs3 = 3 * Dq;
    const ushort* qbase = qkv + (size_t)(b * Tq) * rs3 + hh * HSq;
    int qra = qa * 64 + w * 16 + lm;
    int qrb = qb * 64 + w * 16 + lm;
    s16x8 aqa0 = *(const s16x8*)(qbase + (size_t)qra * rs3 + quad * 8);
    s16x8 aqa1 = *(const s16x8*)(qbase + (size_t)qra * rs3 + 32 + quad * 8);
    s16x8 aqb0 = *(const s16x8*)(qbase + (size_t)qrb * rs3 + quad * 8);
    s16x8 aqb1 = *(const s16x8*)(qbase + (size_t)qrb * rs3 + 32 + quad * 8);

    s16x8 ones;
#pragma unroll
    for (int j = 0; j < 8; j++) ones[j] = (short)0x3F80;

    f32x4 zero = {0.f, 0.f, 0.f, 0.f};
    f32x4 oa[4], ob[4];
#pragma unroll
    for (int nt = 0; nt < 4; nt++) { oa[nt] = zero; ob[nt] = zero; }
    f32x4 la = zero, lb = zero;

    const ushort* kbase = qkv + (size_t)(b * Tq) * rs3 + Dq + hh * HSq;
    const ushort* vtb = VtG + (size_t)((b * Hq + hh) * HSq) * Tq;

    int kr = tid >> 3, kc = (tid & 7) * 8;
    int vh = tid >> 2, vc0 = (tid & 3) * 8;
    int vswz = (((vh >> 3) ^ vh) & 7) << 3;

    s16x8 kp0 = *(const s16x8*)(kbase + (size_t)kr * rs3 + kc);
    s16x8 kp1 = *(const s16x8*)(kbase + (size_t)(kr + 32) * rs3 + kc);
    s16x8 vp0 = *(const s16x8*)(vtb + (size_t)vh * Tq + vc0);
    s16x8 vp1 = *(const s16x8*)(vtb + (size_t)vh * Tq + vc0 + 32);

    auto do_tile = [&](const s16x8& aq0, const s16x8& aq1,
                       f32x4 (&o_acc)[4], f32x4& l_acc, int diag) {
        f32x4 sacc[4];
#pragma unroll
        for (int kt2 = 0; kt2 < 4; kt2++) {
            const ushort* krp = &Ks[(kt2 * 16 + lm) * 72 + quad * 8];
            s16x8 bk0 = *(const s16x8*)krp;
            s16x8 bk1 = *(const s16x8*)(krp + 32);
            f32x4 t = __builtin_amdgcn_mfma_f32_16x16x32_bf16(aq0, bk0, zero, 0, 0, 0);
            sacc[kt2] = __builtin_amdgcn_mfma_f32_16x16x32_bf16(aq1, bk1, t, 0, 0, 0);
        }
        if (diag) {
#pragma unroll
            for (int kt2 = 0; kt2 < 4; kt2++)
#pragma unroll
                for (int r = 0; r < 4; r++)
                    if (kt2 * 16 + lm > w * 16 + quad * 4 + r) sacc[kt2][r] = -1e30f;
        }
#pragma unroll
        for (int kt2 = 0; kt2 < 4; kt2++)
#pragma unroll
            for (int r = 0; r < 4; r++)
                Ps[(w * 16 + quad * 4 + r) * 72 + kt2 * 16 + lm] = f2bf(__expf(sacc[kt2][r]));

        s16x8 ap0 = *(const s16x8*)&Ps[(w * 16 + lm) * 72 + quad * 8];
        s16x8 ap1 = *(const s16x8*)&Ps[(w * 16 + lm) * 72 + 32 + quad * 8];

#pragma unroll
        for (int nt = 0; nt < 4; nt++) {
            int n = nt * 16 + lm;
            int swz = (((n >> 3) ^ n) & 7) << 3;
            s16x8 bv0 = *(const s16x8*)&Vt[n * 64 + ((quad * 8) ^ swz)];
            s16x8 bv1 = *(const s16x8*)&Vt[n * 64 + ((32 + quad * 8) ^ swz)];
            f32x4 t = __builtin_amdgcn_mfma_f32_16x16x32_bf16(ap0, bv0, o_acc[nt], 0, 0, 0);
            o_acc[nt] = __builtin_amdgcn_mfma_f32_16x16x32_bf16(ap1, bv1, t, 0, 0, 0);
        }
        f32x4 t2 = __builtin_amdgcn_mfma_f32_16x16x32_bf16(ap0, ones, l_acc, 0, 0, 0);
        l_acc = __builtin_amdgcn_mfma_f32_16x16x32_bf16(ap1, ones, t2, 0, 0, 0);
    };

    for (int kt = 0; kt <= qb; kt++) {
        __syncthreads();
        *(s16x8*)&Ks[kr * 72 + kc] = kp0;
        *(s16x8*)&Ks[(kr + 32) * 72 + kc] = kp1;
        *(s16x8*)&Vt[vh * 64 + (vc0 ^ vswz)] = vp0;
        *(s16x8*)&Vt[vh * 64 + ((vc0 + 32) ^ vswz)] = vp1;
        __syncthreads();

        if (kt < qb) {
            const ushort* kb = kbase + (size_t)((kt + 1) * 64) * rs3;
            kp0 = *(const s16x8*)(kb + (size_t)kr * rs3 + kc);
            kp1 = *(const s16x8*)(kb + (size_t)(kr + 32) * rs3 + kc);
            const ushort* vb = vtb + (size_t)vh * Tq + (kt + 1) * 64;
            vp0 = *(const s16x8*)(vb + vc0);
            vp1 = *(const s16x8*)(vb + vc0 + 32);
        }

        do_tile(aqb0, aqb1, ob, lb, kt == qb);
        if (kt <= qa)
            do_tile(aqa0, aqa1, oa, la, kt == qa);
    }

#pragma unroll
    for (int r = 0; r < 4; r++) {
        float inva = 1.f / la[r];
        float invb = 1.f / lb[r];
        size_t rowa = (size_t)(b * Tq + qa * 64 + w * 16 + quad * 4 + r);
        size_t rowb = (size_t)(b * Tq + qb * 64 + w * 16 + quad * 4 + r);
#pragma unroll
        for (int nt = 0; nt < 4; nt++) {
            o16[rowa * Dq + hh * HSq + nt * 16 + lm] = f2bf(oa[nt][r] * inva);
            o16[rowb * Dq + hh * HSq + nt * 16 + lm] = f2bf(ob[nt][r] * invb);
        }
    }
}

extern "C" void kernel_launch(void* const* d_in, const int* in_sizes, int n_in,
                              void* d_out, int out_size, void* d_ws, size_t ws_size,
                              hipStream_t stream) {
    const float* x   = (const float*)d_in[0];
    const float* Wq  = (const float*)d_in[1];
    const float* Wk  = (const float*)d_in[2];
    const float* Wv  = (const float*)d_in[3];
    const float* Wp  = (const float*)d_in[4];
    const float* bp  = (const float*)d_in[5];
    const float* W1  = (const float*)d_in[6];
    const float* b1  = (const float*)d_in[7];
    const float* W2  = (const float*)d_in[8];
    const float* b2  = (const float*)d_in[9];
    const float* g1  = (const float*)d_in[10];
    const float* be1 = (const float*)d_in[11];
    const float* g2  = (const float*)d_in[12];
    const float* be2 = (const float*)d_in[13];
    float* out = (float*)d_out;

    const size_t MB = 1u << 20;
    char* ws = (char*)d_ws;
    float*  slotA = (float*)(ws);              // [0,32)   LN1 out -> LN2 out, fp32
    ushort* qkv   = (ushort*)(ws + 32 * MB);   // [32,80)  qkv bf16 (V third unused)
    float*  pbuf  = (float*)(ws + 32 * MB);    // [32,64)  proj out fp32 (qkv dead after attn)
    ushort* u16   = (ushort*)(ws + 32 * MB);   // [32,96)  FF1 out bf16 (pbuf dead after LN2)
    ushort* slotC = (ushort*)(ws + 96 * MB);   // [96,112) h16 -> o16 -> h2_16, bf16
    ushort* WqkvT = (ushort*)(ws + 112 * MB);  // 6 MB
    ushort* WpT   = (ushort*)(ws + 118 * MB);  // 2 MB
    ushort* W1T   = (ushort*)(ws + 120 * MB);  // 8 MB
    ushort* W2T   = (ushort*)(ws + 128 * MB);  // 8 MB
    ushort* VtG   = (ushort*)(ws + 136 * MB);  // 16 MB V^T bf16 [B*H*HS][T]

    const int rows = Bq * Tq;                  // 8192

    hipLaunchKernelGGL(repack_qkvT, dim3(3 * 16 * 16), dim3(256), 0, stream, Wq, Wk, Wv, WqkvT);
    hipLaunchKernelGGL(transpose_cvt, dim3(Dq / 64, Dq / 64), dim3(256), 0, stream, Wp, WpT, Dq, Dq);
    hipLaunchKernelGGL(transpose_cvt, dim3(4 * Dq / 64, Dq / 64), dim3(256), 0, stream, W1, W1T, Dq, 4 * Dq);
    hipLaunchKernelGGL(transpose_cvt, dim3(Dq / 64, 4 * Dq / 64), dim3(256), 0, stream, W2, W2T, 4 * Dq, Dq);

    // 1. LN1
    hipLaunchKernelGGL(ln_bf16, dim3(rows), dim3(256), 0, stream, x, g1, be1, slotA, slotC);
    // 2. QKV GEMM (8-phase 256^2) -> Q,K into qkv bf16; V transposed into VtG (32x12=384 blocks)
    hipLaunchKernelGGL(gemm_8ph, dim3((rows / 256) * (3 * Dq / 256)), dim3(512), 0, stream,
                       slotC, WqkvT, (const float*)nullptr, (const float*)nullptr, (void*)qkv, VtG,
                       rows, 3 * Dq, Dq, Dq, 3 * Dq, 0, 1);
    // 3. attention (complement-paired q-tiles) -> slotC bf16
    hipLaunchKernelGGL(attn_mfma, dim3(Bq * Hq * 16), dim3(256), 0, stream, qkv, VtG, slotC);
    // 4. proj + bias + residual(slotA) -> pbuf fp32  (2-phase, 64x4=256 blocks, full machine)
    hipLaunchKernelGGL(gemm_mp, dim3((rows / 128) * (Dq / 256)), dim3(512), 0, stream,
                       slotC, WpT, bp, slotA, (void*)pbuf, (ushort*)nullptr,
                       rows, Dq, Dq, Dq, Dq, 0, 0);
    // 5. LN2
    hipLaunchKernelGGL(ln_bf16, dim3(rows), dim3(256), 0, stream, pbuf, g2, be2, slotA, slotC);
    // 6. FF1 + bias + relu (8-phase) -> u16 bf16  (32x16=512 blocks, 2 clean rounds)
    hipLaunchKernelGGL(gemm_8ph, dim3((rows / 256) * (4 * Dq / 256)), dim3(512), 0, stream,
                       slotC, W1T, b1, (const float*)nullptr, (void*)u16, (ushort*)nullptr,
                       rows, 4 * Dq, Dq, Dq, 4 * Dq, 1, 1);
    // 7. FF2 + bias + residual(slotA) (8-phase) -> out fp32  (32x4=128 blocks)
    hipLaunchKernelGGL(gemm_8ph, dim3((rows / 256) * (Dq / 256)), dim3(512), 0, stream,
                       u16, W2T, b2, slotA, (void*)out, (ushort*)nullptr,
                       rows, Dq, 4 * Dq, 4 * Dq, Dq, 0, 0);
}

// Round 5
// 544.836 us; speedup vs baseline: 1.0121x; 1.0121x over previous
//
#include <hip/hip_runtime.h>
#include <hip/hip_bf16.h>

#define Bq 4
#define Tq 2048
#define Dq 1024
#define Hq 16
#define HSq 64
#define EPSq 1e-5f

typedef __attribute__((ext_vector_type(8))) short s16x8;
typedef __attribute__((ext_vector_type(4))) float f32x4;

#define GLL16(g, l)                                                        \
    __builtin_amdgcn_global_load_lds(                                      \
        (const __attribute__((address_space(1))) void*)(g),                \
        (__attribute__((address_space(3))) void*)(l), 16, 0, 0)

#define PH_BAR() do { __builtin_amdgcn_sched_barrier(0);                   \
                      __builtin_amdgcn_s_barrier();                        \
                      __builtin_amdgcn_sched_barrier(0); } while (0)

__device__ __forceinline__ ushort f2bf(float f) {
    union { float f; unsigned u; } x; x.f = f;
    unsigned r = x.u + 0x7fffu + ((x.u >> 16) & 1u);
    return (ushort)(r >> 16);
}

// ---------------- LayerNorm: fp32 out + bf16 out ----------------
__global__ __launch_bounds__(256) void ln_bf16(const float* __restrict__ x,
                                               const float* __restrict__ g,
                                               const float* __restrict__ bb,
                                               float* __restrict__ y,
                                               ushort* __restrict__ y16) {
    __shared__ float sdata[8];
    int row = blockIdx.x;
    const float4* xr = (const float4*)(x + (size_t)row * Dq);
    float4 v = xr[threadIdx.x];
    float s  = v.x + v.y + v.z + v.w;
    float ss = v.x*v.x + v.y*v.y + v.z*v.z + v.w*v.w;
    for (int off = 32; off; off >>= 1) {
        s  += __shfl_down(s,  off);
        ss += __shfl_down(ss, off);
    }
    int lane = threadIdx.x & 63, wid = threadIdx.x >> 6;
    if (lane == 0) { sdata[wid] = s; sdata[4 + wid] = ss; }
    __syncthreads();
    if (threadIdx.x == 0) {
        sdata[0] = sdata[0] + sdata[1] + sdata[2] + sdata[3];
        sdata[4] = sdata[4] + sdata[5] + sdata[6] + sdata[7];
    }
    __syncthreads();
    float mu  = sdata[0] * (1.f / Dq);
    float var = sdata[4] * (1.f / Dq) - mu * mu;
    float inv = rsqrtf(var + EPSq);
    float4 gv = ((const float4*)g)[threadIdx.x];
    float4 bv = ((const float4*)bb)[threadIdx.x];
    float4 o;
    o.x = (v.x - mu) * inv * gv.x + bv.x;
    o.y = (v.y - mu) * inv * gv.y + bv.y;
    o.z = (v.z - mu) * inv * gv.z + bv.z;
    o.w = (v.w - mu) * inv * gv.w + bv.w;
    ((float4*)(y + (size_t)row * Dq))[threadIdx.x] = o;
    ushort4 u4;
    u4.x = f2bf(o.x); u4.y = f2bf(o.y); u4.z = f2bf(o.z); u4.w = f2bf(o.w);
    *(ushort4*)(y16 + (size_t)row * Dq + threadIdx.x * 4) = u4;
}

// ---------------- repack Wq/Wk/Wv [H,D,HS] -> bf16 [3D][D] transposed; Wq scaled by 1/32 ----------------
__global__ __launch_bounds__(256) void repack_qkvT(const float* __restrict__ Wqm,
                                                   const float* __restrict__ Wkm,
                                                   const float* __restrict__ Wvm,
                                                   ushort* __restrict__ out) {
    __shared__ float tile[64][65];
    int bid = blockIdx.x;          // p(3) x hh(16) x kt(16)
    int p  = bid >> 8;
    int hh = (bid >> 4) & 15;
    int kt = bid & 15;
    int k0 = kt * 64;
    const float* W = (p == 0) ? Wqm : ((p == 1) ? Wkm : Wvm);
    float scale = (p == 0) ? 0.03125f : 1.0f;
    int j  = threadIdx.x & 63;
    int i0 = threadIdx.x >> 6;
#pragma unroll
    for (int r = 0; r < 16; r++) {
        int i = r * 4 + i0;
        tile[i][j] = W[(size_t)hh * (Dq * HSq) + (size_t)(k0 + i) * HSq + j];
    }
    __syncthreads();
#pragma unroll
    for (int r = 0; r < 16; r++) {
        int i = r * 4 + i0;
        out[(size_t)(p * Dq + hh * HSq + i) * Dq + k0 + j] = f2bf(tile[j][i] * scale);
    }
}

// ---------------- transpose+cvt: in fp32 [K][N] -> out bf16 [N][K] ----------------
__global__ __launch_bounds__(256) void transpose_cvt(const float* __restrict__ in,
                                                     ushort* __restrict__ out,
                                                     int K, int N) {
    __shared__ float tile[64][65];
    int k0 = blockIdx.y * 64, n0 = blockIdx.x * 64;
    int j  = threadIdx.x & 63;
    int i0 = threadIdx.x >> 6;
#pragma unroll
    for (int r = 0; r < 16; r++) {
        int i = r * 4 + i0;
        tile[i][j] = in[(size_t)(k0 + i) * N + n0 + j];
    }
    __syncthreads();
#pragma unroll
    for (int r = 0; r < 16; r++) {
        int i = r * 4 + i0;
        out[(size_t)(n0 + i) * K + k0 + j] = f2bf(tile[j][i]);
    }
}

// ---------------- bf16 MFMA GEMM, counted-vmcnt 2-phase, 2 blocks/CU ----------------
// C = A[M,K] @ BT[N,K]^T (+bias)(+resid)(+relu).
// BM=BN=128, BK=64, 256 thr (2x2 waves, 64x64 out/wave, acc[4][4]).
// LDS = 80 KiB exactly: A double-buffered (2 x 16 KB), B triple-buffered
// (3 x 16 KB) -> TWO blocks/CU (160 KiB total), so one block's vmcnt-gate /
// barrier stall overlaps the other block's MFMA (m114 mechanism; round-4
// showed 1-block/CU deep pipelines stall with all pipes <25% at our K=1024).
// Schedule = round-3-proven 2-phase ledger, re-parameterized: per K-tile t,
// ph0 reads A+B(n0-1) frags and stages A(t+1) [4 GLL]; ph1 reads B(n2-3) and
// stages B(t+2) [4 GLL]; gate vmcnt(4) leaves exactly B(t+2) in flight
// (drains A(t+1), B(t+1)); vmcnt(0) only at t=nkt-2. XOR-swizzle
// (chunk ^= row&7) via pre-swizzled global source + same XOR on ds_read_b128
// (round-3-verified: 0 bank conflicts).
// If vtg != null, col-tiles with col0 >= 2048 (V of the QKV GEMM) are
// written TRANSPOSED to vtg as bf16 [B*H*HS][T] with packed ushort4 stores.
__global__ __launch_bounds__(256, 2) void gemm_bf16(const ushort* __restrict__ A,
                                                    const ushort* __restrict__ BT,
                                                    const float* __restrict__ bias,
                                                    const float* __restrict__ resid,
                                                    void* __restrict__ Cp,
                                                    ushort* __restrict__ vtg,
                                                    int M, int N, int K,
                                                    int lda, int ldc,
                                                    int relu, int out_bf16) {
    // A: 2 slots x [128][64] = 2 x 8192 ushorts; B: 3 slots x [128][64]
    __shared__ ushort lds[2 * 8192 + 3 * 8192];    // 40960 ushorts = 80 KiB
    ushort* Alds = lds;
    ushort* Blds = lds + 2 * 8192;

    int tid = threadIdx.x;
    int w = tid >> 6, lane = tid & 63;
    int lm = lane & 15, quad = lane >> 4;
    int wm = w >> 1, wn = w & 1;                   // 2 x 2 wave grid

    // XCD-aware block swizzle: same-XCD blocks walk row-tiles of one col-tile
    int nwg = gridDim.x;
    int bid = blockIdx.x;
    int wk = bid;
    if ((nwg & 7) == 0) { int cpx = nwg >> 3; wk = (bid & 7) * cpx + (bid >> 3); }
    int mtiles = M >> 7;
    int rt = wk % mtiles, ct = wk / mtiles;
    int row0 = rt << 7, col0 = ct << 7;

    // staging source (pre-swizzled): thread covers LDS bytes tid*16 of each
    // 4 KB sweep; row within sweep = tid>>3, phys chunk = tid&7, logical
    // chunk = phys ^ (row&7)
    int cswz = (lane & 7) ^ (lane >> 3);
    int srow = w * 8 + (lane >> 3);                // 0..31
    const ushort* pA = A  + (size_t)(row0 + srow) * lda + cswz * 8;
    const ushort* pB = BT + (size_t)(col0 + srow) * K  + cswz * 8;

    auto stageA = [&](int slot, int t) {           // 128x64 tile, 4 GLL/thread
#pragma unroll
        for (int s = 0; s < 4; s++)
            GLL16(pA + (size_t)t * 64 + (size_t)(s * 32) * lda,
                  Alds + slot * 8192 + s * 2048 + w * 512);
    };
    auto stageB = [&](int slot, int t) {
#pragma unroll
        for (int s = 0; s < 4; s++)
            GLL16(pB + (size_t)t * 64 + (size_t)(s * 32) * K,
                  Blds + slot * 8192 + s * 2048 + w * 512);
    };

    // swizzled ds_read offsets (ushort units): frag row&7 == lm&7
    int swq0 = (quad * 8) ^ ((lm & 7) << 3);
    int swq1 = (32 + quad * 8) ^ ((lm & 7) << 3);

    f32x4 zero = {0.f, 0.f, 0.f, 0.f};
    f32x4 acc[4][4];
#pragma unroll
    for (int i = 0; i < 4; i++)
#pragma unroll
        for (int jj = 0; jj < 4; jj++) acc[i][jj] = zero;

    int nkt = K >> 6;                              // >= 16 here

    // prologue: A(0)->s0, B(0)->s0, B(1)->s1; gate leaves B(1) in flight
    stageA(0, 0);
    stageB(0, 0);
    stageB(1, 1);
    __builtin_amdgcn_sched_barrier(0);
    asm volatile("s_waitcnt vmcnt(4)" ::: "memory");
    __builtin_amdgcn_s_barrier();
    __builtin_amdgcn_sched_barrier(0);

    int sA = 0, sB = 0;
    for (int t = 0; t < nkt; ++t) {
        const bool stA = (t + 1 < nkt);
        const bool stB = (t + 2 < nkt);
        int sB2 = sB + 2; if (sB2 >= 3) sB2 -= 3;
        const ushort* Ab = Alds + sA * 8192 + (wm * 64 + lm) * 64;
        const ushort* Bb = Blds + sB * 8192 + (wn * 64 + lm) * 64;
        s16x8 a[4][2], b0[2][2], b1[2][2];

        // ---- phase 0: all A frags + B n0-1; stage A(t+1) ----
#pragma unroll
        for (int m = 0; m < 4; m++) {
            a[m][0] = *(const s16x8*)(Ab + m * 1024 + swq0);
            a[m][1] = *(const s16x8*)(Ab + m * 1024 + swq1);
        }
#pragma unroll
        for (int nf = 0; nf < 2; nf++) {
            b0[nf][0] = *(const s16x8*)(Bb + nf * 1024 + swq0);
            b0[nf][1] = *(const s16x8*)(Bb + nf * 1024 + swq1);
        }
        if (stA) stageA(sA ^ 1, t + 1);
        PH_BAR();
        __builtin_amdgcn_s_setprio(1);
#pragma unroll
        for (int m = 0; m < 4; m++)
#pragma unroll
            for (int nf = 0; nf < 2; nf++) {
                f32x4 tt = __builtin_amdgcn_mfma_f32_16x16x32_bf16(a[m][0], b0[nf][0], acc[m][nf], 0, 0, 0);
                acc[m][nf] = __builtin_amdgcn_mfma_f32_16x16x32_bf16(a[m][1], b0[nf][1], tt, 0, 0, 0);
            }
        __builtin_amdgcn_s_setprio(0);
        PH_BAR();

        // ---- phase 1: B n2-3; stage B(t+2) ----
#pragma unroll
        for (int nf = 0; nf < 2; nf++) {
            b1[nf][0] = *(const s16x8*)(Bb + (nf + 2) * 1024 + swq0);
            b1[nf][1] = *(const s16x8*)(Bb + (nf + 2) * 1024 + swq1);
        }
        if (stB) stageB(sB2, t + 2);
        PH_BAR();
        __builtin_amdgcn_s_setprio(1);
#pragma unroll
        for (int m = 0; m < 4; m++)
#pragma unroll
            for (int nf = 0; nf < 2; nf++) {
                f32x4 tt = __builtin_amdgcn_mfma_f32_16x16x32_bf16(a[m][0], b1[nf][0], acc[m][nf + 2], 0, 0, 0);
                acc[m][nf + 2] = __builtin_amdgcn_mfma_f32_16x16x32_bf16(a[m][1], b1[nf][1], tt, 0, 0, 0);
            }
        __builtin_amdgcn_s_setprio(0);
        __builtin_amdgcn_sched_barrier(0);
        if (stB)      { asm volatile("s_waitcnt vmcnt(4)" ::: "memory"); }
        else if (stA) { asm volatile("s_waitcnt vmcnt(0)" ::: "memory"); }
        if (stA) {
            __builtin_amdgcn_s_barrier();
            __builtin_amdgcn_sched_barrier(0);
        }

        sA ^= 1;
        sB += 1; if (sB >= 3) sB -= 3;
    }

    if (vtg && col0 >= 2048) {
        // V part: write transposed [B*H*HS][T], 4 consecutive t per ushort4
#pragma unroll
        for (int m = 0; m < 4; m++) {
            int r0 = row0 + wm * 64 + m * 16 + quad * 4;   // t base (mult of 4)
            int bb = r0 >> 11;
            int t  = r0 & (Tq - 1);
#pragma unroll
            for (int nf = 0; nf < 4; nf++) {
                int hsg = col0 - 2048 + wn * 64 + nf * 16 + lm;   // 0..1023
                ushort4 u;
                u.x = f2bf(acc[m][nf][0]);
                u.y = f2bf(acc[m][nf][1]);
                u.z = f2bf(acc[m][nf][2]);
                u.w = f2bf(acc[m][nf][3]);
                *(ushort4*)(vtg + ((size_t)(bb * Hq + (hsg >> 6)) * HSq + (hsg & 63)) * Tq + t) = u;
            }
        }
        return;
    }

    float bcol[4];
#pragma unroll
    for (int nf = 0; nf < 4; nf++)
        bcol[nf] = bias ? bias[col0 + wn * 64 + nf * 16 + lm] : 0.f;

#pragma unroll
    for (int m = 0; m < 4; m++) {
#pragma unroll
        for (int p = 0; p < 4; p++) {
            int r = row0 + wm * 64 + m * 16 + quad * 4 + p;
#pragma unroll
            for (int nf = 0; nf < 4; nf++) {
                int cc = col0 + wn * 64 + nf * 16 + lm;
                float v = acc[m][nf][p] + bcol[nf];
                if (relu) v = fmaxf(v, 0.f);
                if (resid) v += resid[(size_t)r * ldc + cc];
                if (out_bf16) ((ushort*)Cp)[(size_t)r * ldc + cc] = f2bf(v);
                else          ((float*)Cp)[(size_t)r * ldc + cc] = v;
            }
        }
    }
}

// ---------------- MFMA flash attention, complement-paired q-tiles ----------------
__global__ __launch_bounds__(256) void attn_mfma(const ushort* __restrict__ qkv,
                                                 const ushort* __restrict__ VtG,
                                                 ushort* __restrict__ o16) {
    __shared__ ushort Ks[64 * 72];
    __shared__ ushort Vt[64 * 64];
    __shared__ ushort Ps[4 * 16 * 72];

    int gid = blockIdx.x;
    int b  = gid >> 8;
    int hh = (gid >> 4) & 15;
    int pr = (gid + 7 * b) & 15;
    int qa = pr;
    int qb = 31 - pr;

    int tid = threadIdx.x;
    int w = tid >> 6, lane = tid & 63;
    int lm = lane & 15, quad = lane >> 4;

    const int rs3 = 3 * Dq;
    const ushort* qbase = qkv + (size_t)(b * Tq) * rs3 + hh * HSq;
    int qra = qa * 64 + w * 16 + lm;
    int qrb = qb * 64 + w * 16 + lm;
    s16x8 aqa0 = *(const s16x8*)(qbase + (size_t)qra * rs3 + quad * 8);
    s16x8 aqa1 = *(const s16x8*)(qbase + (size_t)qra * rs3 + 32 + quad * 8);
    s16x8 aqb0 = *(const s16x8*)(qbase + (size_t)qrb * rs3 + quad * 8);
    s16x8 aqb1 = *(const s16x8*)(qbase + (size_t)qrb * rs3 + 32 + quad * 8);

    s16x8 ones;
#pragma unroll
    for (int j = 0; j < 8; j++) ones[j] = (short)0x3F80;

    f32x4 zero = {0.f, 0.f, 0.f, 0.f};
    f32x4 oa[4], ob[4];
#pragma unroll
    for (int nt = 0; nt < 4; nt++) { oa[nt] = zero; ob[nt] = zero; }
    f32x4 la = zero, lb = zero;

    const ushort* kbase = qkv + (size_t)(b * Tq) * rs3 + Dq + hh * HSq;
    const ushort* vtb = VtG + (size_t)((b * Hq + hh) * HSq) * Tq;

    int kr = tid >> 3, kc = (tid & 7) * 8;
    int vh = tid >> 2, vc0 = (tid & 3) * 8;
    int vswz = (((vh >> 3) ^ vh) & 7) << 3;

    s16x8 kp0 = *(const s16x8*)(kbase + (size_t)kr * rs3 + kc);
    s16x8 kp1 = *(const s16x8*)(kbase + (size_t)(kr + 32) * rs3 + kc);
    s16x8 vp0 = *(const s16x8*)(vtb + (size_t)vh * Tq + vc0);
    s16x8 vp1 = *(const s16x8*)(vtb + (size_t)vh * Tq + vc0 + 32);

    auto do_tile = [&](const s16x8& aq0, const s16x8& aq1,
                       f32x4 (&o_acc)[4], f32x4& l_acc, int diag) {
        f32x4 sacc[4];
#pragma unroll
        for (int kt2 = 0; kt2 < 4; kt2++) {
            const ushort* krp = &Ks[(kt2 * 16 + lm) * 72 + quad * 8];
            s16x8 bk0 = *(const s16x8*)krp;
            s16x8 bk1 = *(const s16x8*)(krp + 32);
            f32x4 t = __builtin_amdgcn_mfma_f32_16x16x32_bf16(aq0, bk0, zero, 0, 0, 0);
            sacc[kt2] = __builtin_amdgcn_mfma_f32_16x16x32_bf16(aq1, bk1, t, 0, 0, 0);
        }
        if (diag) {
#pragma unroll
            for (int kt2 = 0; kt2 < 4; kt2++)
#pragma unroll
                for (int r = 0; r < 4; r++)
                    if (kt2 * 16 + lm > w * 16 + quad * 4 + r) sacc[kt2][r] = -1e30f;
        }
#pragma unroll
        for (int kt2 = 0; kt2 < 4; kt2++)
#pragma unroll
            for (int r = 0; r < 4; r++)
                Ps[(w * 16 + quad * 4 + r) * 72 + kt2 * 16 + lm] = f2bf(__expf(sacc[kt2][r]));

        s16x8 ap0 = *(const s16x8*)&Ps[(w * 16 + lm) * 72 + quad * 8];
        s16x8 ap1 = *(const s16x8*)&Ps[(w * 16 + lm) * 72 + 32 + quad * 8];

#pragma unroll
        for (int nt = 0; nt < 4; nt++) {
            int n = nt * 16 + lm;
            int swz = (((n >> 3) ^ n) & 7) << 3;
            s16x8 bv0 = *(const s16x8*)&Vt[n * 64 + ((quad * 8) ^ swz)];
            s16x8 bv1 = *(const s16x8*)&Vt[n * 64 + ((32 + quad * 8) ^ swz)];
            f32x4 t = __builtin_amdgcn_mfma_f32_16x16x32_bf16(ap0, bv0, o_acc[nt], 0, 0, 0);
            o_acc[nt] = __builtin_amdgcn_mfma_f32_16x16x32_bf16(ap1, bv1, t, 0, 0, 0);
        }
        f32x4 t2 = __builtin_amdgcn_mfma_f32_16x16x32_bf16(ap0, ones, l_acc, 0, 0, 0);
        l_acc = __builtin_amdgcn_mfma_f32_16x16x32_bf16(ap1, ones, t2, 0, 0, 0);
    };

    for (int kt = 0; kt <= qb; kt++) {
        __syncthreads();
        *(s16x8*)&Ks[kr * 72 + kc] = kp0;
        *(s16x8*)&Ks[(kr + 32) * 72 + kc] = kp1;
        *(s16x8*)&Vt[vh * 64 + (vc0 ^ vswz)] = vp0;
        *(s16x8*)&Vt[vh * 64 + ((vc0 + 32) ^ vswz)] = vp1;
        __syncthreads();

        if (kt < qb) {
            const ushort* kb = kbase + (size_t)((kt + 1) * 64) * rs3;
            kp0 = *(const s16x8*)(kb + (size_t)kr * rs3 + kc);
            kp1 = *(const s16x8*)(kb + (size_t)(kr + 32) * rs3 + kc);
            const ushort* vb = vtb + (size_t)vh * Tq + (kt + 1) * 64;
            vp0 = *(const s16x8*)(vb + vc0);
            vp1 = *(const s16x8*)(vb + vc0 + 32);
        }

        do_tile(aqb0, aqb1, ob, lb, kt == qb);
        if (kt <= qa)
            do_tile(aqa0, aqa1, oa, la, kt == qa);
    }

#pragma unroll
    for (int r = 0; r < 4; r++) {
        float inva = 1.f / la[r];
        float invb = 1.f / lb[r];
        size_t rowa = (size_t)(b * Tq + qa * 64 + w * 16 + quad * 4 + r);
        size_t rowb = (size_t)(b * Tq + qb * 64 + w * 16 + quad * 4 + r);
#pragma unroll
        for (int nt = 0; nt < 4; nt++) {
            o16[rowa * Dq + hh * HSq + nt * 16 + lm] = f2bf(oa[nt][r] * inva);
            o16[rowb * Dq + hh * HSq + nt * 16 + lm] = f2bf(ob[nt][r] * invb);
        }
    }
}

extern "C" void kernel_launch(void* const* d_in, const int* in_sizes, int n_in,
                              void* d_out, int out_size, void* d_ws, size_t ws_size,
                              hipStream_t stream) {
    const float* x   = (const float*)d_in[0];
    const float* Wq  = (const float*)d_in[1];
    const float* Wk  = (const float*)d_in[2];
    const float* Wv  = (const float*)d_in[3];
    const float* Wp  = (const float*)d_in[4];
    const float* bp  = (const float*)d_in[5];
    const float* W1  = (const float*)d_in[6];
    const float* b1  = (const float*)d_in[7];
    const float* W2  = (const float*)d_in[8];
    const float* b2  = (const float*)d_in[9];
    const float* g1  = (const float*)d_in[10];
    const float* be1 = (const float*)d_in[11];
    const float* g2  = (const float*)d_in[12];
    const float* be2 = (const float*)d_in[13];
    float* out = (float*)d_out;

    const size_t MB = 1u << 20;
    char* ws = (char*)d_ws;
    float*  slotA = (float*)(ws);              // [0,32)   LN1 out -> LN2 out, fp32
    ushort* qkv   = (ushort*)(ws + 32 * MB);   // [32,80)  qkv bf16 (V third unused)
    float*  pbuf  = (float*)(ws + 32 * MB);    // [32,64)  proj out fp32 (qkv dead after attn)
    ushort* u16   = (ushort*)(ws + 32 * MB);   // [32,96)  FF1 out bf16 (pbuf dead after LN2)
    ushort* slotC = (ushort*)(ws + 96 * MB);   // [96,112) h16 -> o16 -> h2_16, bf16
    ushort* WqkvT = (ushort*)(ws + 112 * MB);  // 6 MB
    ushort* WpT   = (ushort*)(ws + 118 * MB);  // 2 MB
    ushort* W1T   = (ushort*)(ws + 120 * MB);  // 8 MB
    ushort* W2T   = (ushort*)(ws + 128 * MB);  // 8 MB
    ushort* VtG   = (ushort*)(ws + 136 * MB);  // 16 MB V^T bf16 [B*H*HS][T]

    const int rows = Bq * Tq;                  // 8192

    hipLaunchKernelGGL(repack_qkvT, dim3(3 * 16 * 16), dim3(256), 0, stream, Wq, Wk, Wv, WqkvT);
    hipLaunchKernelGGL(transpose_cvt, dim3(Dq / 64, Dq / 64), dim3(256), 0, stream, Wp, WpT, Dq, Dq);
    hipLaunchKernelGGL(transpose_cvt, dim3(4 * Dq / 64, Dq / 64), dim3(256), 0, stream, W1, W1T, Dq, 4 * Dq);
    hipLaunchKernelGGL(transpose_cvt, dim3(Dq / 64, 4 * Dq / 64), dim3(256), 0, stream, W2, W2T, 4 * Dq, Dq);

    // 1. LN1
    hipLaunchKernelGGL(ln_bf16, dim3(rows), dim3(256), 0, stream, x, g1, be1, slotA, slotC);
    // 2. QKV GEMM -> Q,K into qkv bf16; V transposed into VtG  (64 x 24 = 1536 blocks)
    hipLaunchKernelGGL(gemm_bf16, dim3((rows / 128) * (3 * Dq / 128)), dim3(256), 0, stream,
                       slotC, WqkvT, (const float*)nullptr, (const float*)nullptr, (void*)qkv, VtG,
                       rows, 3 * Dq, Dq, Dq, 3 * Dq, 0, 1);
    // 3. attention (complement-paired q-tiles) -> slotC bf16
    hipLaunchKernelGGL(attn_mfma, dim3(Bq * Hq * 16), dim3(256), 0, stream, qkv, VtG, slotC);
    // 4. proj + bias + residual(slotA) -> pbuf fp32  (64 x 8 = 512 blocks)
    hipLaunchKernelGGL(gemm_bf16, dim3((rows / 128) * (Dq / 128)), dim3(256), 0, stream,
                       slotC, WpT, bp, slotA, (void*)pbuf, (ushort*)nullptr,
                       rows, Dq, Dq, Dq, Dq, 0, 0);
    // 5. LN2
    hipLaunchKernelGGL(ln_bf16, dim3(rows), dim3(256), 0, stream, pbuf, g2, be2, slotA, slotC);
    // 6. FF1 + bias + relu -> u16 bf16  (64 x 32 = 2048 blocks)
    hipLaunchKernelGGL(gemm_bf16, dim3((rows / 128) * (4 * Dq / 128)), dim3(256), 0, stream,
                       slotC, W1T, b1, (const float*)nullptr, (void*)u16, (ushort*)nullptr,
                       rows, 4 * Dq, Dq, Dq, 4 * Dq, 1, 1);
    // 7. FF2 + bias + residual(slotA) -> out fp32  (64 x 8 = 512 blocks)
    hipLaunchKernelGGL(gemm_bf16, dim3((rows / 128) * (Dq / 128)), dim3(256), 0, stream,
                       u16, W2T, b2, slotA, (void*)out, (ushort*)nullptr,
                       rows, Dq, 4 * Dq, 4 * Dq, Dq, 0, 0);
}

// Round 6
// 515.830 us; speedup vs baseline: 1.0690x; 1.0562x over previous
//
#include <hip/hip_runtime.h>
#include <hip/hip_bf16.h>

#define Bq 4
#define Tq 2048
#define Dq 1024
#define Hq 16
#define HSq 64
#define EPSq 1e-5f

typedef __attribute__((ext_vector_type(8))) short s16x8;
typedef __attribute__((ext_vector_type(4))) float f32x4;

#define GLL16(g, l)                                                        \
    __builtin_amdgcn_global_load_lds(                                      \
        (const __attribute__((address_space(1))) void*)(g),                \
        (__attribute__((address_space(3))) void*)(l), 16, 0, 0)

#define PH_BAR() do { __builtin_amdgcn_sched_barrier(0);                   \
                      __builtin_amdgcn_s_barrier();                        \
                      __builtin_amdgcn_sched_barrier(0); } while (0)

__device__ __forceinline__ ushort f2bf(float f) {
    union { float f; unsigned u; } x; x.f = f;
    unsigned r = x.u + 0x7fffu + ((x.u >> 16) & 1u);
    return (ushort)(r >> 16);
}

// ---------------- LayerNorm: fp32 out + bf16 out ----------------
__global__ __launch_bounds__(256) void ln_bf16(const float* __restrict__ x,
                                               const float* __restrict__ g,
                                               const float* __restrict__ bb,
                                               float* __restrict__ y,
                                               ushort* __restrict__ y16) {
    __shared__ float sdata[8];
    int row = blockIdx.x;
    const float4* xr = (const float4*)(x + (size_t)row * Dq);
    float4 v = xr[threadIdx.x];
    float s  = v.x + v.y + v.z + v.w;
    float ss = v.x*v.x + v.y*v.y + v.z*v.z + v.w*v.w;
    for (int off = 32; off; off >>= 1) {
        s  += __shfl_down(s,  off);
        ss += __shfl_down(ss, off);
    }
    int lane = threadIdx.x & 63, wid = threadIdx.x >> 6;
    if (lane == 0) { sdata[wid] = s; sdata[4 + wid] = ss; }
    __syncthreads();
    if (threadIdx.x == 0) {
        sdata[0] = sdata[0] + sdata[1] + sdata[2] + sdata[3];
        sdata[4] = sdata[4] + sdata[5] + sdata[6] + sdata[7];
    }
    __syncthreads();
    float mu  = sdata[0] * (1.f / Dq);
    float var = sdata[4] * (1.f / Dq) - mu * mu;
    float inv = rsqrtf(var + EPSq);
    float4 gv = ((const float4*)g)[threadIdx.x];
    float4 bv = ((const float4*)bb)[threadIdx.x];
    float4 o;
    o.x = (v.x - mu) * inv * gv.x + bv.x;
    o.y = (v.y - mu) * inv * gv.y + bv.y;
    o.z = (v.z - mu) * inv * gv.z + bv.z;
    o.w = (v.w - mu) * inv * gv.w + bv.w;
    ((float4*)(y + (size_t)row * Dq))[threadIdx.x] = o;
    ushort4 u4;
    u4.x = f2bf(o.x); u4.y = f2bf(o.y); u4.z = f2bf(o.z); u4.w = f2bf(o.w);
    *(ushort4*)(y16 + (size_t)row * Dq + threadIdx.x * 4) = u4;
}

// ---------------- repack Wq/Wk/Wv [H,D,HS] -> bf16 [3D][D] transposed; Wq scaled by 1/32 ----------------
__global__ __launch_bounds__(256) void repack_qkvT(const float* __restrict__ Wqm,
                                                   const float* __restrict__ Wkm,
                                                   const float* __restrict__ Wvm,
                                                   ushort* __restrict__ out) {
    __shared__ float tile[64][65];
    int bid = blockIdx.x;          // p(3) x hh(16) x kt(16)
    int p  = bid >> 8;
    int hh = (bid >> 4) & 15;
    int kt = bid & 15;
    int k0 = kt * 64;
    const float* W = (p == 0) ? Wqm : ((p == 1) ? Wkm : Wvm);
    float scale = (p == 0) ? 0.03125f : 1.0f;
    int j  = threadIdx.x & 63;
    int i0 = threadIdx.x >> 6;
#pragma unroll
    for (int r = 0; r < 16; r++) {
        int i = r * 4 + i0;
        tile[i][j] = W[(size_t)hh * (Dq * HSq) + (size_t)(k0 + i) * HSq + j];
    }
    __syncthreads();
#pragma unroll
    for (int r = 0; r < 16; r++) {
        int i = r * 4 + i0;
        out[(size_t)(p * Dq + hh * HSq + i) * Dq + k0 + j] = f2bf(tile[j][i] * scale);
    }
}

// ---------------- transpose+cvt: in fp32 [K][N] -> out bf16 [N][K] ----------------
__global__ __launch_bounds__(256) void transpose_cvt(const float* __restrict__ in,
                                                     ushort* __restrict__ out,
                                                     int K, int N) {
    __shared__ float tile[64][65];
    int k0 = blockIdx.y * 64, n0 = blockIdx.x * 64;
    int j  = threadIdx.x & 63;
    int i0 = threadIdx.x >> 6;
#pragma unroll
    for (int r = 0; r < 16; r++) {
        int i = r * 4 + i0;
        tile[i][j] = in[(size_t)(k0 + i) * N + n0 + j];
    }
    __syncthreads();
#pragma unroll
    for (int r = 0; r < 16; r++) {
        int i = r * 4 + i0;
        out[(size_t)(n0 + i) * K + k0 + j] = f2bf(tile[j][i]);
    }
}

// ---------------- bf16 MFMA GEMM, counted-vmcnt 2-phase, 4 blocks/CU ----------------
// C = A[M,K] @ BT[N,K]^T (+bias)(+resid)(+relu).
// BM=BN=128, BK=32, 256 thr (2x2 waves, 64x64 out/wave, acc[4][4]).
// LDS = 40 KiB: A double-buffered (2 x 8 KB), B triple-buffered (3 x 8 KB)
// -> FOUR blocks/CU (160 KiB), 16 waves/CU: one block's gate/barrier stall
// overlaps three other blocks' MFMA (m114 mechanism; r4/r5 counters showed
// all pipes idle -> latency-bound). Ledger (unit = 2 GLL, same shape as the
// r3/r5-proven one): prologue stages A(0),B(0),B(1), gate vmcnt(2);
// per iter t: ph0 reads A+B(n0-1) frags, stages A(t+1); ph1 reads B(n2-3),
// stages B(t+2); gate vmcnt(2) (induction: start-of-iter outstanding =
// B(t+1) only); vmcnt(0) at t=nkt-2. No LDS swizzle needed at BK=32: each
// frag ds_read_b128 covers a contiguous aligned 1 KiB (16 rows x 64 B) ->
// conflict-free by construction.
// Band-major block map (L2 A-panel reuse): XCD x owns row-tiles [8x,8x+8);
// within XCD srt varies fastest (stride sr) then ct -> co-resident blocks
// share <=sr A row-panels (sr=8 @K=1024: 2 MB; sr=4 @K=4096: 4 MB, both
// L2-resident) while B panels stream.
// If vtg != null, col-tiles with col0 >= 2048 (V of the QKV GEMM) are
// written TRANSPOSED to vtg as bf16 [B*H*HS][T] with packed ushort4 stores.
__global__ __launch_bounds__(256, 4) void gemm_bf16(const ushort* __restrict__ A,
                                                    const ushort* __restrict__ BT,
                                                    const float* __restrict__ bias,
                                                    const float* __restrict__ resid,
                                                    void* __restrict__ Cp,
                                                    ushort* __restrict__ vtg,
                                                    int M, int N, int K,
                                                    int lda, int ldc,
                                                    int relu, int out_bf16,
                                                    int sr) {
    // A: 2 slots x [128][32] = 2 x 4096 ushorts; B: 3 slots x [128][32]
    __shared__ ushort lds[2 * 4096 + 3 * 4096];    // 20480 ushorts = 40 KiB
    ushort* Alds = lds;
    ushort* Blds = lds + 2 * 4096;

    int tid = threadIdx.x;
    int w = tid >> 6, lane = tid & 63;
    int lm = lane & 15, quad = lane >> 4;
    int wm = w >> 1, wn = w & 1;                   // 2 x 2 wave grid

    // band-major block map (requires mtiles==64, nwg%8==0; else fallback)
    int bid = blockIdx.x;
    int mtiles = M >> 7, ntiles = N >> 7;
    int rt, ct;
    if (mtiles == 64 && (gridDim.x & 7) == 0) {
        int xcd = bid & 7, l = bid >> 3;
        int band = l / (sr * ntiles);
        int rem  = l - band * sr * ntiles;
        ct = rem / sr;
        int srt = rem - ct * sr;
        rt = xcd * 8 + band * sr + srt;
    } else {
        rt = bid % mtiles; ct = bid / mtiles;
    }
    int row0 = rt << 7, col0 = ct << 7;

    // staging: thread covers row w*16+(lane>>2) (+64), chunk lane&3 (16B)
    int srow = w * 16 + (lane >> 2);
    int schk = lane & 3;
    const ushort* pA = A  + (size_t)(row0 + srow) * lda + schk * 8;
    const ushort* pB = BT + (size_t)(col0 + srow) * K  + schk * 8;

    auto stageA = [&](int slot, int t) {           // 128x32 tile, 2 GLL/thread
        GLL16(pA + (size_t)t * 32, Alds + slot * 4096 + w * 512);
        GLL16(pA + (size_t)t * 32 + (size_t)64 * lda, Alds + slot * 4096 + 2048 + w * 512);
    };
    auto stageB = [&](int slot, int t) {
        GLL16(pB + (size_t)t * 32, Blds + slot * 4096 + w * 512);
        GLL16(pB + (size_t)t * 32 + (size_t)64 * K, Blds + slot * 4096 + 2048 + w * 512);
    };

    f32x4 zero = {0.f, 0.f, 0.f, 0.f};
    f32x4 acc[4][4];
#pragma unroll
    for (int i = 0; i < 4; i++)
#pragma unroll
        for (int jj = 0; jj < 4; jj++) acc[i][jj] = zero;

    int nkt = K >> 5;                              // K-tiles of 32 (>= 32 here)

    // prologue: A(0)->s0, B(0)->s0, B(1)->s1; gate leaves B(1) in flight
    stageA(0, 0);
    stageB(0, 0);
    stageB(1, 1);
    __builtin_amdgcn_sched_barrier(0);
    asm volatile("s_waitcnt vmcnt(2)" ::: "memory");
    __builtin_amdgcn_s_barrier();
    __builtin_amdgcn_sched_barrier(0);

    int sA = 0, sB = 0;
    for (int t = 0; t < nkt; ++t) {
        const bool stA = (t + 1 < nkt);
        const bool stB = (t + 2 < nkt);
        int sB2 = sB + 2; if (sB2 >= 3) sB2 -= 3;
        const ushort* Ab = Alds + sA * 4096 + (wm * 64 + lm) * 32;
        const ushort* Bb = Blds + sB * 4096 + (wn * 64 + lm) * 32;
        s16x8 a[4], b0[2], b1[2];

        // ---- phase 0: all A frags + B n0-1; stage A(t+1) ----
#pragma unroll
        for (int m = 0; m < 4; m++)
            a[m] = *(const s16x8*)(Ab + m * 512 + quad * 8);
#pragma unroll
        for (int nf = 0; nf < 2; nf++)
            b0[nf] = *(const s16x8*)(Bb + nf * 512 + quad * 8);
        if (stA) stageA(sA ^ 1, t + 1);
        PH_BAR();
        __builtin_amdgcn_s_setprio(1);
#pragma unroll
        for (int m = 0; m < 4; m++)
#pragma unroll
            for (int nf = 0; nf < 2; nf++)
                acc[m][nf] = __builtin_amdgcn_mfma_f32_16x16x32_bf16(a[m], b0[nf], acc[m][nf], 0, 0, 0);
        __builtin_amdgcn_s_setprio(0);
        PH_BAR();

        // ---- phase 1: B n2-3; stage B(t+2) ----
#pragma unroll
        for (int nf = 0; nf < 2; nf++)
            b1[nf] = *(const s16x8*)(Bb + (nf + 2) * 512 + quad * 8);
        if (stB) stageB(sB2, t + 2);
        PH_BAR();
        __builtin_amdgcn_s_setprio(1);
#pragma unroll
        for (int m = 0; m < 4; m++)
#pragma unroll
            for (int nf = 0; nf < 2; nf++)
                acc[m][nf + 2] = __builtin_amdgcn_mfma_f32_16x16x32_bf16(a[m], b1[nf], acc[m][nf + 2], 0, 0, 0);
        __builtin_amdgcn_s_setprio(0);
        __builtin_amdgcn_sched_barrier(0);
        if (stB)      { asm volatile("s_waitcnt vmcnt(2)" ::: "memory"); }
        else if (stA) { asm volatile("s_waitcnt vmcnt(0)" ::: "memory"); }
        if (stA) {
            __builtin_amdgcn_s_barrier();
            __builtin_amdgcn_sched_barrier(0);
        }

        sA ^= 1;
        sB += 1; if (sB >= 3) sB -= 3;
    }

    if (vtg && col0 >= 2048) {
        // V part: write transposed [B*H*HS][T], 4 consecutive t per ushort4
#pragma unroll
        for (int m = 0; m < 4; m++) {
            int r0 = row0 + wm * 64 + m * 16 + quad * 4;   // t base (mult of 4)
            int bb = r0 >> 11;
            int t  = r0 & (Tq - 1);
#pragma unroll
            for (int nf = 0; nf < 4; nf++) {
                int hsg = col0 - 2048 + wn * 64 + nf * 16 + lm;   // 0..1023
                ushort4 u;
                u.x = f2bf(acc[m][nf][0]);
                u.y = f2bf(acc[m][nf][1]);
                u.z = f2bf(acc[m][nf][2]);
                u.w = f2bf(acc[m][nf][3]);
                *(ushort4*)(vtg + ((size_t)(bb * Hq + (hsg >> 6)) * HSq + (hsg & 63)) * Tq + t) = u;
            }
        }
        return;
    }

    float bcol[4];
#pragma unroll
    for (int nf = 0; nf < 4; nf++)
        bcol[nf] = bias ? bias[col0 + wn * 64 + nf * 16 + lm] : 0.f;

#pragma unroll
    for (int m = 0; m < 4; m++) {
#pragma unroll
        for (int p = 0; p < 4; p++) {
            int r = row0 + wm * 64 + m * 16 + quad * 4 + p;
#pragma unroll
            for (int nf = 0; nf < 4; nf++) {
                int cc = col0 + wn * 64 + nf * 16 + lm;
                float v = acc[m][nf][p] + bcol[nf];
                if (relu) v = fmaxf(v, 0.f);
                if (resid) v += resid[(size_t)r * ldc + cc];
                if (out_bf16) ((ushort*)Cp)[(size_t)r * ldc + cc] = f2bf(v);
                else          ((float*)Cp)[(size_t)r * ldc + cc] = v;
            }
        }
    }
}

// ---------------- MFMA flash attention, complement-paired q-tiles ----------------
__global__ __launch_bounds__(256) void attn_mfma(const ushort* __restrict__ qkv,
                                                 const ushort* __restrict__ VtG,
                                                 ushort* __restrict__ o16) {
    __shared__ ushort Ks[64 * 72];
    __shared__ ushort Vt[64 * 64];
    __shared__ ushort Ps[4 * 16 * 72];

    int gid = blockIdx.x;
    int b  = gid >> 8;
    int hh = (gid >> 4) & 15;
    int pr = (gid + 7 * b) & 15;
    int qa = pr;
    int qb = 31 - pr;

    int tid = threadIdx.x;
    int w = tid >> 6, lane = tid & 63;
    int lm = lane & 15, quad = lane >> 4;

    const int rs3 = 3 * Dq;
    const ushort* qbase = qkv + (size_t)(b * Tq) * rs3 + hh * HSq;
    int qra = qa * 64 + w * 16 + lm;
    int qrb = qb * 64 + w * 16 + lm;
    s16x8 aqa0 = *(const s16x8*)(qbase + (size_t)qra * rs3 + quad * 8);
    s16x8 aqa1 = *(const s16x8*)(qbase + (size_t)qra * rs3 + 32 + quad * 8);
    s16x8 aqb0 = *(const s16x8*)(qbase + (size_t)qrb * rs3 + quad * 8);
    s16x8 aqb1 = *(const s16x8*)(qbase + (size_t)qrb * rs3 + 32 + quad * 8);

    s16x8 ones;
#pragma unroll
    for (int j = 0; j < 8; j++) ones[j] = (short)0x3F80;

    f32x4 zero = {0.f, 0.f, 0.f, 0.f};
    f32x4 oa[4], ob[4];
#pragma unroll
    for (int nt = 0; nt < 4; nt++) { oa[nt] = zero; ob[nt] = zero; }
    f32x4 la = zero, lb = zero;

    const ushort* kbase = qkv + (size_t)(b * Tq) * rs3 + Dq + hh * HSq;
    const ushort* vtb = VtG + (size_t)((b * Hq + hh) * HSq) * Tq;

    int kr = tid >> 3, kc = (tid & 7) * 8;
    int vh = tid >> 2, vc0 = (tid & 3) * 8;
    int vswz = (((vh >> 3) ^ vh) & 7) << 3;

    s16x8 kp0 = *(const s16x8*)(kbase + (size_t)kr * rs3 + kc);
    s16x8 kp1 = *(const s16x8*)(kbase + (size_t)(kr + 32) * rs3 + kc);
    s16x8 vp0 = *(const s16x8*)(vtb + (size_t)vh * Tq + vc0);
    s16x8 vp1 = *(const s16x8*)(vtb + (size_t)vh * Tq + vc0 + 32);

    auto do_tile = [&](const s16x8& aq0, const s16x8& aq1,
                       f32x4 (&o_acc)[4], f32x4& l_acc, int diag) {
        f32x4 sacc[4];
#pragma unroll
        for (int kt2 = 0; kt2 < 4; kt2++) {
            const ushort* krp = &Ks[(kt2 * 16 + lm) * 72 + quad * 8];
            s16x8 bk0 = *(const s16x8*)krp;
            s16x8 bk1 = *(const s16x8*)(krp + 32);
            f32x4 t = __builtin_amdgcn_mfma_f32_16x16x32_bf16(aq0, bk0, zero, 0, 0, 0);
            sacc[kt2] = __builtin_amdgcn_mfma_f32_16x16x32_bf16(aq1, bk1, t, 0, 0, 0);
        }
        if (diag) {
#pragma unroll
            for (int kt2 = 0; kt2 < 4; kt2++)
#pragma unroll
                for (int r = 0; r < 4; r++)
                    if (kt2 * 16 + lm > w * 16 + quad * 4 + r) sacc[kt2][r] = -1e30f;
        }
#pragma unroll
        for (int kt2 = 0; kt2 < 4; kt2++)
#pragma unroll
            for (int r = 0; r < 4; r++)
                Ps[(w * 16 + quad * 4 + r) * 72 + kt2 * 16 + lm] = f2bf(__expf(sacc[kt2][r]));

        s16x8 ap0 = *(const s16x8*)&Ps[(w * 16 + lm) * 72 + quad * 8];
        s16x8 ap1 = *(const s16x8*)&Ps[(w * 16 + lm) * 72 + 32 + quad * 8];

#pragma unroll
        for (int nt = 0; nt < 4; nt++) {
            int n = nt * 16 + lm;
            int swz = (((n >> 3) ^ n) & 7) << 3;
            s16x8 bv0 = *(const s16x8*)&Vt[n * 64 + ((quad * 8) ^ swz)];
            s16x8 bv1 = *(const s16x8*)&Vt[n * 64 + ((32 + quad * 8) ^ swz)];
            f32x4 t = __builtin_amdgcn_mfma_f32_16x16x32_bf16(ap0, bv0, o_acc[nt], 0, 0, 0);
            o_acc[nt] = __builtin_amdgcn_mfma_f32_16x16x32_bf16(ap1, bv1, t, 0, 0, 0);
        }
        f32x4 t2 = __builtin_amdgcn_mfma_f32_16x16x32_bf16(ap0, ones, l_acc, 0, 0, 0);
        l_acc = __builtin_amdgcn_mfma_f32_16x16x32_bf16(ap1, ones, t2, 0, 0, 0);
    };

    for (int kt = 0; kt <= qb; kt++) {
        __syncthreads();
        *(s16x8*)&Ks[kr * 72 + kc] = kp0;
        *(s16x8*)&Ks[(kr + 32) * 72 + kc] = kp1;
        *(s16x8*)&Vt[vh * 64 + (vc0 ^ vswz)] = vp0;
        *(s16x8*)&Vt[vh * 64 + ((vc0 + 32) ^ vswz)] = vp1;
        __syncthreads();

        if (kt < qb) {
            const ushort* kb = kbase + (size_t)((kt + 1) * 64) * rs3;
            kp0 = *(const s16x8*)(kb + (size_t)kr * rs3 + kc);
            kp1 = *(const s16x8*)(kb + (size_t)(kr + 32) * rs3 + kc);
            const ushort* vb = vtb + (size_t)vh * Tq + (kt + 1) * 64;
            vp0 = *(const s16x8*)(vb + vc0);
            vp1 = *(const s16x8*)(vb + vc0 + 32);
        }

        do_tile(aqb0, aqb1, ob, lb, kt == qb);
        if (kt <= qa)
            do_tile(aqa0, aqa1, oa, la, kt == qa);
    }

#pragma unroll
    for (int r = 0; r < 4; r++) {
        float inva = 1.f / la[r];
        float invb = 1.f / lb[r];
        size_t rowa = (size_t)(b * Tq + qa * 64 + w * 16 + quad * 4 + r);
        size_t rowb = (size_t)(b * Tq + qb * 64 + w * 16 + quad * 4 + r);
#pragma unroll
        for (int nt = 0; nt < 4; nt++) {
            o16[rowa * Dq + hh * HSq + nt * 16 + lm] = f2bf(oa[nt][r] * inva);
            o16[rowb * Dq + hh * HSq + nt * 16 + lm] = f2bf(ob[nt][r] * invb);
        }
    }
}

extern "C" void kernel_launch(void* const* d_in, const int* in_sizes, int n_in,
                              void* d_out, int out_size, void* d_ws, size_t ws_size,
                              hipStream_t stream) {
    const float* x   = (const float*)d_in[0];
    const float* Wq  = (const float*)d_in[1];
    const float* Wk  = (const float*)d_in[2];
    const float* Wv  = (const float*)d_in[3];
    const float* Wp  = (const float*)d_in[4];
    const float* bp  = (const float*)d_in[5];
    const float* W1  = (const float*)d_in[6];
    const float* b1  = (const float*)d_in[7];
    const float* W2  = (const float*)d_in[8];
    const float* b2  = (const float*)d_in[9];
    const float* g1  = (const float*)d_in[10];
    const float* be1 = (const float*)d_in[11];
    const float* g2  = (const float*)d_in[12];
    const float* be2 = (const float*)d_in[13];
    float* out = (float*)d_out;

    const size_t MB = 1u << 20;
    char* ws = (char*)d_ws;
    float*  slotA = (float*)(ws);              // [0,32)   LN1 out -> LN2 out, fp32
    ushort* qkv   = (ushort*)(ws + 32 * MB);   // [32,80)  qkv bf16 (V third unused)
    float*  pbuf  = (float*)(ws + 32 * MB);    // [32,64)  proj out fp32 (qkv dead after attn)
    ushort* u16   = (ushort*)(ws + 32 * MB);   // [32,96)  FF1 out bf16 (pbuf dead after LN2)
    ushort* slotC = (ushort*)(ws + 96 * MB);   // [96,112) h16 -> o16 -> h2_16, bf16
    ushort* WqkvT = (ushort*)(ws + 112 * MB);  // 6 MB
    ushort* WpT   = (ushort*)(ws + 118 * MB);  // 2 MB
    ushort* W1T   = (ushort*)(ws + 120 * MB);  // 8 MB
    ushort* W2T   = (ushort*)(ws + 128 * MB);  // 8 MB
    ushort* VtG   = (ushort*)(ws + 136 * MB);  // 16 MB V^T bf16 [B*H*HS][T]

    const int rows = Bq * Tq;                  // 8192

    hipLaunchKernelGGL(repack_qkvT, dim3(3 * 16 * 16), dim3(256), 0, stream, Wq, Wk, Wv, WqkvT);
    hipLaunchKernelGGL(transpose_cvt, dim3(Dq / 64, Dq / 64), dim3(256), 0, stream, Wp, WpT, Dq, Dq);
    hipLaunchKernelGGL(transpose_cvt, dim3(4 * Dq / 64, Dq / 64), dim3(256), 0, stream, W1, W1T, Dq, 4 * Dq);
    hipLaunchKernelGGL(transpose_cvt, dim3(Dq / 64, 4 * Dq / 64), dim3(256), 0, stream, W2, W2T, 4 * Dq, Dq);

    // 1. LN1
    hipLaunchKernelGGL(ln_bf16, dim3(rows), dim3(256), 0, stream, x, g1, be1, slotA, slotC);
    // 2. QKV GEMM -> Q,K into qkv bf16; V transposed into VtG  (64 x 24 = 1536 blocks)
    hipLaunchKernelGGL(gemm_bf16, dim3((rows / 128) * (3 * Dq / 128)), dim3(256), 0, stream,
                       slotC, WqkvT, (const float*)nullptr, (const float*)nullptr, (void*)qkv, VtG,
                       rows, 3 * Dq, Dq, Dq, 3 * Dq, 0, 1, 8);
    // 3. attention (complement-paired q-tiles) -> slotC bf16
    hipLaunchKernelGGL(attn_mfma, dim3(Bq * Hq * 16), dim3(256), 0, stream, qkv, VtG, slotC);
    // 4. proj + bias + residual(slotA) -> pbuf fp32  (64 x 8 = 512 blocks)
    hipLaunchKernelGGL(gemm_bf16, dim3((rows / 128) * (Dq / 128)), dim3(256), 0, stream,
                       slotC, WpT, bp, slotA, (void*)pbuf, (ushort*)nullptr,
                       rows, Dq, Dq, Dq, Dq, 0, 0, 8);
    // 5. LN2
    hipLaunchKernelGGL(ln_bf16, dim3(rows), dim3(256), 0, stream, pbuf, g2, be2, slotA, slotC);
    // 6. FF1 + bias + relu -> u16 bf16  (64 x 32 = 2048 blocks)
    hipLaunchKernelGGL(gemm_bf16, dim3((rows / 128) * (4 * Dq / 128)), dim3(256), 0, stream,
                       slotC, W1T, b1, (const float*)nullptr, (void*)u16, (ushort*)nullptr,
                       rows, 4 * Dq, Dq, Dq, 4 * Dq, 1, 1, 8);
    // 7. FF2 + bias + residual(slotA) -> out fp32  (64 x 8 = 512 blocks; sr=4 for K=4096)
    hipLaunchKernelGGL(gemm_bf16, dim3((rows / 128) * (Dq / 128)), dim3(256), 0, stream,
                       u16, W2T, b2, slotA, (void*)out, (ushort*)nullptr,
                       rows, Dq, 4 * Dq, 4 * Dq, Dq, 0, 0, 4);
}